// Round 7
// baseline (264.642 us; speedup 1.0000x reference)
//
#include <hip/hip_runtime.h>

#define SQ 4096      // sequence length = 64*64
#define CCH 256      // channels
#define NH 8         // heads
#define HD 32        // head dim
#define LN_EPS 1e-5f
#define NSPLIT 4     // kv splits per head

typedef __bf16 bf16x8 __attribute__((ext_vector_type(8)));
typedef float f32x4 __attribute__((ext_vector_type(4)));
typedef short s16x4 __attribute__((ext_vector_type(4)));
using bf16 = __bf16;

#define LOG2E 1.4426950408889634f

#if defined(__has_builtin)
#if __has_builtin(__builtin_amdgcn_mfma_f32_16x16x16bf16_1k)
#define HAVE_MFMA16 1
#else
#define HAVE_MFMA16 0
#endif
#else
#define HAVE_MFMA16 0
#endif

// ---------------------------------------------------------------------------
// Tile transpose + fp32->bf16 convert: src [R][Ccol] f32 -> dst [Ccol][R] bf16
// ---------------------------------------------------------------------------
__device__ __forceinline__ void tile_tc(const float* __restrict__ src, bf16* __restrict__ dst,
                                        int R, int Ccol, int ti, int tj) {
    __shared__ float t[32][33];
    const int tx = threadIdx.x & 31;
    const int ty = threadIdx.x >> 5;   // 0..7
    const int i0 = ti * 32, j0 = tj * 32;
    #pragma unroll
    for (int i = 0; i < 32; i += 8)
        t[ty + i][tx] = src[(size_t)(i0 + ty + i) * Ccol + j0 + tx];
    __syncthreads();
    #pragma unroll
    for (int i = 0; i < 32; i += 8)
        dst[(size_t)(j0 + ty + i) * R + i0 + tx] = (bf16)t[tx][ty + i];
}

// inputs: x,y [C][S] f32 -> xT,yT [S][C] bf16
__global__ __launch_bounds__(256)
void cvt_inputs(const float* __restrict__ x, const float* __restrict__ y,
                bf16* __restrict__ xT, bf16* __restrict__ yT) {
    const float* s = blockIdx.z ? y : x;
    bf16* d = blockIdx.z ? yT : xT;
    tile_tc(s, d, CCH, SQ, blockIdx.y, blockIdx.x);
}

// weights: W [K][N] f32 -> WT [N][K] bf16, all six in one launch (768 tiles)
__global__ __launch_bounds__(256)
void cvt_weights(const float* Wq, const float* Wk, const float* Wv, const float* Wo,
                 const float* W1, const float* W2,
                 bf16* WqT, bf16* WkT, bf16* WvT, bf16* WoT, bf16* W1T, bf16* W2T) {
    const int id = blockIdx.x;
    if (id < 256) {
        const int w = id >> 6, local = id & 63;
        const float* s = (w == 0) ? Wq : (w == 1) ? Wk : (w == 2) ? Wv : Wo;
        bf16* d = (w == 0) ? WqT : (w == 1) ? WkT : (w == 2) ? WvT : WoT;
        tile_tc(s, d, 256, 256, local >> 3, local & 7);
    } else if (id < 512) {
        const int local = id - 256;
        tile_tc(W1, W1T, 256, 1024, local >> 5, local & 31);
    } else {
        const int local = id - 512;
        tile_tc(W2, W2T, 1024, 256, local >> 3, local & 7);
    }
}

// ---------------------------------------------------------------------------
// MFMA GEMM: C[M,N] = A @ B + bias. A [M][K] bf16, BT [N][K] bf16.
// 64x64 tile, 4 waves (2x2), register-direct fragments.
// OUT_MODE: 0 = f32; 2 = bf16 (scaled by bscale); 3 = bf16 transposed [N][SQ].
// ---------------------------------------------------------------------------
template <int K, int OUT_MODE, bool RELU>
__global__ __launch_bounds__(256)
void gemm_mfma(const bf16* __restrict__ A, const bf16* __restrict__ BT,
               const float* __restrict__ bias, float* __restrict__ Cf,
               bf16* __restrict__ Cb, int N, float bscale) {
    const int tid = threadIdx.x;
    const int w = tid >> 6, l = tid & 63;
    const int l15 = l & 15, lg = l >> 4;
    const int m0 = blockIdx.x * 64 + (w >> 1) * 32;
    const int n0 = blockIdx.y * 64 + (w & 1) * 32;

    f32x4 acc[2][2] = {};
    const bf16* a0 = &A[(size_t)(m0 + l15) * K + lg * 8];
    const bf16* b0 = &BT[(size_t)(n0 + l15) * K + lg * 8];

    for (int k0 = 0; k0 < K; k0 += 32) {
        bf16x8 a[2], b[2];
        a[0] = *reinterpret_cast<const bf16x8*>(a0 + k0);
        a[1] = *reinterpret_cast<const bf16x8*>(a0 + (size_t)16 * K + k0);
        b[0] = *reinterpret_cast<const bf16x8*>(b0 + k0);
        b[1] = *reinterpret_cast<const bf16x8*>(b0 + (size_t)16 * K + k0);
        #pragma unroll
        for (int i = 0; i < 2; ++i)
            #pragma unroll
            for (int j = 0; j < 2; ++j)
                acc[i][j] = __builtin_amdgcn_mfma_f32_16x16x32_bf16(a[i], b[j], acc[i][j], 0, 0, 0);
    }

    #pragma unroll
    for (int i = 0; i < 2; ++i) {
        #pragma unroll
        for (int j = 0; j < 2; ++j) {
            const int col = n0 + j * 16 + l15;
            const float bs = bias[col];
            #pragma unroll
            for (int r = 0; r < 4; ++r) {
                const int row = m0 + i * 16 + lg * 4 + r;
                float val = acc[i][j][r] + bs;
                if (RELU) val = fmaxf(val, 0.f);
                if constexpr (OUT_MODE == 0)
                    Cf[(size_t)row * N + col] = val;
                if constexpr (OUT_MODE == 2)
                    Cb[(size_t)row * N + col] = (bf16)(val * bscale);
                if constexpr (OUT_MODE == 3)
                    Cb[(size_t)col * SQ + row] = (bf16)val;
            }
        }
    }
}

// ---------------------------------------------------------------------------
// MFMA flash attention v6: swapped QK^T + no-max softmax + REGISTER-ONLY PV.
// Key insight: the K=16 MFMA (16x16x16_bf16) has 4-element lane k-groups
// (k = lg*4+j), which exactly matches the D-layout quad of the swapped QK^T
// (lane l: q=l15, keys lg*4+r).  So packed P quads feed PV directly as the
// B-operand -- zero LDS, no fragment exchange, no lgkmcnt round-trip.
// kb pre-scaled by LOG2E/sqrt(32); p = exp2(s) (scores bounded, softmax is
// shift-invariant); l reduced once at end; partials merge as sum(o)/sum(l).
// ---------------------------------------------------------------------------
__global__ __launch_bounds__(256)
void flash_attn6(const bf16* __restrict__ qb, const bf16* __restrict__ kb,
                 const bf16* __restrict__ vT, bf16* __restrict__ Op,
                 float* __restrict__ Lp) {
    const int h  = blockIdx.y;
    const int q0 = blockIdx.x * 64;
    const int sp = blockIdx.z;
    const int tid = threadIdx.x;
    const int w = tid >> 6, l = tid & 63;
    const int l15 = l & 15, lg = l >> 4;

#if !HAVE_MFMA16
    __shared__ unsigned int Sb[4][8][72];
#endif

    bf16x8 aq = *reinterpret_cast<const bf16x8*>(
        &qb[(size_t)(q0 + w * 16 + l15) * CCH + h * HD + lg * 8]);

    float lac = 0.f;
    f32x4 oaccT[2] = {{0.f, 0.f, 0.f, 0.f}, {0.f, 0.f, 0.f, 0.f}};

    const bf16* kfrag = &kb[(size_t)l15 * CCH + h * HD + lg * 8];
#if HAVE_MFMA16
    const bf16* vfrag16 = &vT[(size_t)(h * HD + l15) * SQ + lg * 4];
#else
    const bf16* vfrag = &vT[(size_t)(h * HD + l15) * SQ + lg * 8];
#endif

    const int kt0 = sp * (SQ / NSPLIT / 64);
    const int kt1 = kt0 + (SQ / NSPLIT / 64);

    for (int kt = kt0; kt < kt1; ++kt) {
        const int kb0 = kt * 64;

        // --- S^T = K·Q^T: lane l -> q-row l15, keys t*16 + lg*4 + r ---
        f32x4 s[4];
        #pragma unroll
        for (int t = 0; t < 4; ++t) {
            bf16x8 kf = *reinterpret_cast<const bf16x8*>(
                kfrag + (size_t)(kb0 + t * 16) * CCH);
            s[t] = __builtin_amdgcn_mfma_f32_16x16x32_bf16(kf, aq, (f32x4){0.f, 0.f, 0.f, 0.f}, 0, 0, 0);
        }

#if HAVE_MFMA16
        // --- p = exp2(s); pack to bf16 quad; PV directly from registers ---
        #pragma unroll
        for (int t = 0; t < 4; ++t) {
            float p0 = exp2f(s[t][0]);
            float p1 = exp2f(s[t][1]);
            float p2 = exp2f(s[t][2]);
            float p3 = exp2f(s[t][3]);
            lac += (p0 + p1) + (p2 + p3);
            unsigned int u0 = __builtin_bit_cast(unsigned int, p0) + 0x8000u;
            unsigned int u1 = __builtin_bit_cast(unsigned int, p1) + 0x8000u;
            unsigned int u2 = __builtin_bit_cast(unsigned int, p2) + 0x8000u;
            unsigned int u3 = __builtin_bit_cast(unsigned int, p3) + 0x8000u;
            union { unsigned int u[2]; s16x4 v; } pb;
            pb.u[0] = __builtin_amdgcn_perm(u1, u0, 0x07060302u);
            pb.u[1] = __builtin_amdgcn_perm(u3, u2, 0x07060302u);
            // PV: O^T[d][q] += V^T[d][k16] · P^T[k16][q]
            #pragma unroll
            for (int dh = 0; dh < 2; ++dh) {
                s16x4 va = *reinterpret_cast<const s16x4*>(
                    vfrag16 + (size_t)dh * 16 * SQ + kb0 + t * 16);
                oaccT[dh] = __builtin_amdgcn_mfma_f32_16x16x16bf16_1k(
                    va, pb.v, oaccT[dh], 0, 0, 0);
            }
        }
#else
        // --- fallback: v5 LDS relayout path ---
        #pragma unroll
        for (int t = 0; t < 4; ++t) {
            float p0 = exp2f(s[t][0]);
            float p1 = exp2f(s[t][1]);
            float p2 = exp2f(s[t][2]);
            float p3 = exp2f(s[t][3]);
            lac += (p0 + p1) + (p2 + p3);
            unsigned int u0 = __builtin_bit_cast(unsigned int, p0) + 0x8000u;
            unsigned int u1 = __builtin_bit_cast(unsigned int, p1) + 0x8000u;
            unsigned int u2 = __builtin_bit_cast(unsigned int, p2) + 0x8000u;
            unsigned int u3 = __builtin_bit_cast(unsigned int, p3) + 0x8000u;
            Sb[w][t * 2 + 0][l] = __builtin_amdgcn_perm(u1, u0, 0x07060302u);
            Sb[w][t * 2 + 1][l] = __builtin_amdgcn_perm(u3, u2, 0x07060302u);
        }
        #pragma unroll
        for (int kh = 0; kh < 2; ++kh) {
            const int sbase = kh * 4 + (lg >> 1) * 2;
            const int i0 = l15 + 16 * ((lg & 1) * 2);
            const int i1 = i0 + 16;
            union { unsigned int u[4]; bf16x8 v; } pb;
            pb.u[0] = Sb[w][sbase + 0][i0];
            pb.u[1] = Sb[w][sbase + 1][i0];
            pb.u[2] = Sb[w][sbase + 0][i1];
            pb.u[3] = Sb[w][sbase + 1][i1];
            #pragma unroll
            for (int dh = 0; dh < 2; ++dh) {
                bf16x8 va = *reinterpret_cast<const bf16x8*>(
                    vfrag + (size_t)dh * 16 * SQ + kb0 + kh * 32);
                oaccT[dh] = __builtin_amdgcn_mfma_f32_16x16x32_bf16(va, pb.v, oaccT[dh], 0, 0, 0);
            }
        }
#endif
    }

    // --- end-of-split: reduce l across the 4 lane-groups; write raw o,l ---
    lac += __shfl_xor(lac, 16);
    lac += __shfl_xor(lac, 32);

    const size_t obase = ((size_t)sp * NH + h) * HD;
    #pragma unroll
    for (int dh = 0; dh < 2; ++dh)
        #pragma unroll
        for (int r = 0; r < 4; ++r)
            Op[(obase + dh * 16 + lg * 4 + r) * SQ + q0 + w * 16 + l15] =
                (bf16)oaccT[dh][r];
    if (lg == 0)
        Lp[((size_t)sp * NH + h) * SQ + q0 + w * 16 + l15] = lac;
}

// ---------------------------------------------------------------------------
// Merge NSPLIT raw partial O^T [d][q] tiles -> atb [S][C] bf16.
// out = (sum_sp o_sp) / (sum_sp l_sp).  Block = (64 q, head).
// ---------------------------------------------------------------------------
__global__ __launch_bounds__(256)
void attn_merge3(const bf16* __restrict__ Op, const float* __restrict__ Lp,
                 bf16* __restrict__ atb) {
    const int h = blockIdx.y;
    const int q0 = blockIdx.x * 64;
    const int t = threadIdx.x;
    __shared__ float sInv[64];
    __shared__ float trans[32][65];

    if (t < 64) {
        float L = 0.f;
        #pragma unroll
        for (int sp = 0; sp < NSPLIT; ++sp)
            L += Lp[((size_t)sp * NH + h) * SQ + q0 + t];
        sInv[t] = 1.0f / L;
    }
    __syncthreads();

    const int q = t & 63, dg = t >> 6;
    float a[8] = {0.f, 0.f, 0.f, 0.f, 0.f, 0.f, 0.f, 0.f};
    for (int sp = 0; sp < NSPLIT; ++sp) {
        const size_t rb = ((size_t)sp * NH + h) * HD;
        #pragma unroll
        for (int i = 0; i < 8; ++i) {
            const int d = i * 4 + dg;
            a[i] += (float)Op[(rb + d) * SQ + q0 + q];
        }
    }
    const float invq = sInv[q];
    #pragma unroll
    for (int i = 0; i < 8; ++i)
        trans[i * 4 + dg][q] = a[i] * invq;
    __syncthreads();

    const int oq = t >> 2, od = (t & 3) * 8;
    bf16x8 o8;
    #pragma unroll
    for (int j = 0; j < 8; ++j) o8[j] = (bf16)trans[od + j][oq];
    *reinterpret_cast<bf16x8*>(&atb[(size_t)(q0 + oq) * CCH + h * HD + od]) = o8;
}

// ---------------------------------------------------------------------------
// Fused residual add + LayerNorm over C=256; optional bf16 secondary output.
// ---------------------------------------------------------------------------
template <typename TA, bool DUAL>
__global__ __launch_bounds__(256)
void add_ln(const TA* __restrict__ a, const float* __restrict__ b,
            const float* __restrict__ g, const float* __restrict__ beta,
            float* __restrict__ out, bf16* __restrict__ outb) {
    const int s = blockIdx.x;
    const int c = threadIdx.x;
    float val = (float)a[(size_t)s * CCH + c] + b[(size_t)s * CCH + c];
    float sum = val, sq = val * val;
    #pragma unroll
    for (int off = 1; off < 64; off <<= 1) {
        sum += __shfl_xor(sum, off);
        sq  += __shfl_xor(sq, off);
    }
    __shared__ float ssum[4], ssq[4];
    int w = c >> 6;
    if ((c & 63) == 0) { ssum[w] = sum; ssq[w] = sq; }
    __syncthreads();
    sum = ssum[0] + ssum[1] + ssum[2] + ssum[3];
    sq  = ssq[0] + ssq[1] + ssq[2] + ssq[3];
    float mu = sum * (1.0f / CCH);
    float var = sq * (1.0f / CCH) - mu * mu;
    float rs = rsqrtf(var + LN_EPS);
    float res = (val - mu) * rs * g[c] + beta[c];
    out[(size_t)s * CCH + c] = res;
    if constexpr (DUAL) outb[(size_t)s * CCH + c] = (bf16)res;
}

// ---------------------------------------------------------------------------
// Final transpose: in [S][C] f32 -> out [C][S] f32
// ---------------------------------------------------------------------------
__global__ __launch_bounds__(256)
void transpose_sc_cs(const float* __restrict__ in, float* __restrict__ out) {
    __shared__ float tile[32][33];
    const int s0 = blockIdx.x * 32;
    const int c0 = blockIdx.y * 32;
    const int tx = threadIdx.x & 31;
    const int ty = threadIdx.x >> 5;
    #pragma unroll
    for (int i = 0; i < 32; i += 8)
        tile[ty + i][tx] = in[(size_t)(s0 + ty + i) * CCH + c0 + tx];
    __syncthreads();
    #pragma unroll
    for (int i = 0; i < 32; i += 8)
        out[(size_t)(c0 + ty + i) * SQ + s0 + tx] = tile[tx][ty + i];
}

// ---------------------------------------------------------------------------
extern "C" void kernel_launch(void* const* d_in, const int* in_sizes, int n_in,
                              void* d_out, int out_size, void* d_ws, size_t ws_size,
                              hipStream_t stream) {
    const float* lidar = (const float*)d_in[0];
    const float* image = (const float*)d_in[1];
    const float* Wq  = (const float*)d_in[2];
    const float* bq  = (const float*)d_in[3];
    const float* Wk  = (const float*)d_in[4];
    const float* bk  = (const float*)d_in[5];
    const float* Wv  = (const float*)d_in[6];
    const float* bv  = (const float*)d_in[7];
    const float* Wo  = (const float*)d_in[8];
    const float* bo  = (const float*)d_in[9];
    const float* g1  = (const float*)d_in[10];
    const float* b1  = (const float*)d_in[11];
    const float* W1  = (const float*)d_in[12];
    const float* bf1 = (const float*)d_in[13];
    const float* W2  = (const float*)d_in[14];
    const float* bf2 = (const float*)d_in[15];
    const float* g2  = (const float*)d_in[16];
    const float* b2  = (const float*)d_in[17];
    float* out = (float*)d_out;

    // workspace layout (aliased; peak 23.5 MB)
    char* ws = (char*)d_ws;
    const size_t KB = 1024, MBy = 1024 * 1024;
    bf16* xT   = (bf16*)(ws + 0);                    // [0,2M)    dead after q-gemm
    bf16* yT   = (bf16*)(ws + 2 * MBy);              // [2,4M)    dead after v-gemm
    bf16* WqT  = (bf16*)(ws + 4 * MBy);              // weights [4,5.5M)
    bf16* WkT  = (bf16*)(ws + 4 * MBy + 128 * KB);
    bf16* WvT  = (bf16*)(ws + 4 * MBy + 256 * KB);
    bf16* WoT  = (bf16*)(ws + 4 * MBy + 384 * KB);
    bf16* W1T  = (bf16*)(ws + 4 * MBy + 512 * KB);
    bf16* W2T  = (bf16*)(ws + 5 * MBy);
    bf16* qb   = (bf16*)(ws + 5 * MBy + 512 * KB);   // [5.5,7.5M)  live -> ln1 (residual)
    bf16* kbb  = (bf16*)(ws + 7 * MBy + 512 * KB);   // [7.5,9.5M)  live -> flash
    bf16* vTb  = (bf16*)(ws + 9 * MBy + 512 * KB);   // [9.5,11.5M) live -> flash
    bf16* Op   = (bf16*)(ws + 11 * MBy + 512 * KB);  // [11.5,19.5M) partials, dead after merge
    float* Lp  = (float*)(ws + 20 * MBy);            // [20,20.5M)
    bf16* atb  = (bf16*)(ws + 0);                    // [0,2M)    reuses xT; dead after Wo
    float* o   = (float*)(ws + 7 * MBy + 512 * KB);  // [7.5,11.5M) reuses kbb/vTb; dead after ln1
    float* ln1 = (float*)(ws + 11 * MBy + 512 * KB); // [11.5,15.5M) reuses Op; live -> ln2
    bf16* ln1b = (bf16*)(ws + 0);                    // [0,2M)    reuses atb; dead after ffn1
    bf16* h1   = (bf16*)(ws + 15 * MBy + 512 * KB);  // [15.5,23.5M) dead after ffn2
    float* h2  = (float*)(ws + 5 * MBy + 512 * KB);  // [5.5,9.5M)  reuses qb/o; dead after ln2
    float* ln2 = (float*)(ws + 0);                   // [0,4M)    reuses ln1b/yT

    // 1/sqrt(32) * log2(e) folded into K -> scores already in log2 domain
    const float qscale = 0.17677669529663687f * 1.4426950408889634f;
    dim3 blk(256);

    cvt_inputs<<<dim3(SQ / 32, CCH / 32, 2), blk, 0, stream>>>(lidar, image, xT, yT);
    cvt_weights<<<dim3(768), blk, 0, stream>>>(Wq, Wk, Wv, Wo, W1, W2,
                                               WqT, WkT, WvT, WoT, W1T, W2T);
    // projections: q bf16 (unscaled, also residual), k bf16 (pre-scaled), v bf16 transposed
    gemm_mfma<256, 2, false><<<dim3(64, 4), blk, 0, stream>>>(xT, WqT, bq, nullptr, qb, 256, 1.f);
    gemm_mfma<256, 2, false><<<dim3(64, 4), blk, 0, stream>>>(yT, WkT, bk, nullptr, kbb, 256, qscale);
    gemm_mfma<256, 3, false><<<dim3(64, 4), blk, 0, stream>>>(yT, WvT, bv, nullptr, vTb, 256, 1.f);
    // attention (split-KV, swapped-operand, no-max softmax, register PV) + merge
    flash_attn6<<<dim3(SQ / 64, NH, NSPLIT), blk, 0, stream>>>(qb, kbb, vTb, Op, Lp);
    attn_merge3<<<dim3(SQ / 64, NH), blk, 0, stream>>>(Op, Lp, atb);
    // output projection
    gemm_mfma<256, 0, false><<<dim3(64, 4), blk, 0, stream>>>(atb, WoT, bo, o, nullptr, 256, 1.f);
    // LN1(q + o) -> f32 + bf16
    add_ln<bf16, true><<<SQ, blk, 0, stream>>>(qb, o, g1, b1, ln1, ln1b);
    // FFN
    gemm_mfma<256, 2, true ><<<dim3(64, 16), blk, 0, stream>>>(ln1b, W1T, bf1, nullptr, h1, 1024, 1.f);
    gemm_mfma<1024, 0, false><<<dim3(64, 4), blk, 0, stream>>>(h1, W2T, bf2, h2, nullptr, 256, 1.f);
    // LN2(ln1 + h2)
    add_ln<float, false><<<SQ, blk, 0, stream>>>(ln1, h2, g2, b2, ln2, nullptr);
    // final [S][C] -> [C][S]
    transpose_sc_cs<<<dim3(SQ / 32, CCH / 32), blk, 0, stream>>>(ln2, out);
}

// Round 8
// 156.002 us; speedup vs baseline: 1.6964x; 1.6964x over previous
//
#include <hip/hip_runtime.h>

#define SQ 4096      // sequence length = 64*64
#define CCH 256      // channels
#define NH 8         // heads
#define HD 32        // head dim
#define LN_EPS 1e-5f
#define NSPLIT 4     // kv splits per head

typedef __bf16 bf16x8 __attribute__((ext_vector_type(8)));
typedef float f32x4 __attribute__((ext_vector_type(4)));
using bf16 = __bf16;

#define LOG2E 1.4426950408889634f

// ---------------------------------------------------------------------------
// Tile transpose + fp32->bf16 convert: src [R][Ccol] f32 -> dst [Ccol][R] bf16
// ---------------------------------------------------------------------------
__device__ __forceinline__ void tile_tc(const float* __restrict__ src, bf16* __restrict__ dst,
                                        int R, int Ccol, int ti, int tj) {
    __shared__ float t[32][33];
    const int tx = threadIdx.x & 31;
    const int ty = threadIdx.x >> 5;   // 0..7
    const int i0 = ti * 32, j0 = tj * 32;
    #pragma unroll
    for (int i = 0; i < 32; i += 8)
        t[ty + i][tx] = src[(size_t)(i0 + ty + i) * Ccol + j0 + tx];
    __syncthreads();
    #pragma unroll
    for (int i = 0; i < 32; i += 8)
        dst[(size_t)(j0 + ty + i) * R + i0 + tx] = (bf16)t[tx][ty + i];
}

// inputs: x,y [C][S] f32 -> xT,yT [S][C] bf16
__global__ __launch_bounds__(256)
void cvt_inputs(const float* __restrict__ x, const float* __restrict__ y,
                bf16* __restrict__ xT, bf16* __restrict__ yT) {
    const float* s = blockIdx.z ? y : x;
    bf16* d = blockIdx.z ? yT : xT;
    tile_tc(s, d, CCH, SQ, blockIdx.y, blockIdx.x);
}

// weights: W [K][N] f32 -> WT [N][K] bf16, all six in one launch (768 tiles)
__global__ __launch_bounds__(256)
void cvt_weights(const float* Wq, const float* Wk, const float* Wv, const float* Wo,
                 const float* W1, const float* W2,
                 bf16* WqT, bf16* WkT, bf16* WvT, bf16* WoT, bf16* W1T, bf16* W2T) {
    const int id = blockIdx.x;
    if (id < 256) {
        const int w = id >> 6, local = id & 63;
        const float* s = (w == 0) ? Wq : (w == 1) ? Wk : (w == 2) ? Wv : Wo;
        bf16* d = (w == 0) ? WqT : (w == 1) ? WkT : (w == 2) ? WvT : WoT;
        tile_tc(s, d, 256, 256, local >> 3, local & 7);
    } else if (id < 512) {
        const int local = id - 256;
        tile_tc(W1, W1T, 256, 1024, local >> 5, local & 31);
    } else {
        const int local = id - 512;
        tile_tc(W2, W2T, 1024, 256, local >> 3, local & 7);
    }
}

// ---------------------------------------------------------------------------
// MFMA GEMM: C[M,N] = A @ B + bias. A [M][K] bf16, BT [N][K] bf16.
// 64x64 tile, 4 waves (2x2), register-direct fragments.
// OUT_MODE: 0 = f32; 2 = bf16 (scaled by bscale); 3 = bf16 transposed [N][SQ].
// ---------------------------------------------------------------------------
template <int K, int OUT_MODE, bool RELU>
__global__ __launch_bounds__(256)
void gemm_mfma(const bf16* __restrict__ A, const bf16* __restrict__ BT,
               const float* __restrict__ bias, float* __restrict__ Cf,
               bf16* __restrict__ Cb, int N, float bscale) {
    const int tid = threadIdx.x;
    const int w = tid >> 6, l = tid & 63;
    const int l15 = l & 15, lg = l >> 4;
    const int m0 = blockIdx.x * 64 + (w >> 1) * 32;
    const int n0 = blockIdx.y * 64 + (w & 1) * 32;

    f32x4 acc[2][2] = {};
    const bf16* a0 = &A[(size_t)(m0 + l15) * K + lg * 8];
    const bf16* b0 = &BT[(size_t)(n0 + l15) * K + lg * 8];

    for (int k0 = 0; k0 < K; k0 += 32) {
        bf16x8 a[2], b[2];
        a[0] = *reinterpret_cast<const bf16x8*>(a0 + k0);
        a[1] = *reinterpret_cast<const bf16x8*>(a0 + (size_t)16 * K + k0);
        b[0] = *reinterpret_cast<const bf16x8*>(b0 + k0);
        b[1] = *reinterpret_cast<const bf16x8*>(b0 + (size_t)16 * K + k0);
        #pragma unroll
        for (int i = 0; i < 2; ++i)
            #pragma unroll
            for (int j = 0; j < 2; ++j)
                acc[i][j] = __builtin_amdgcn_mfma_f32_16x16x32_bf16(a[i], b[j], acc[i][j], 0, 0, 0);
    }

    #pragma unroll
    for (int i = 0; i < 2; ++i) {
        #pragma unroll
        for (int j = 0; j < 2; ++j) {
            const int col = n0 + j * 16 + l15;
            const float bs = bias[col];
            #pragma unroll
            for (int r = 0; r < 4; ++r) {
                const int row = m0 + i * 16 + lg * 4 + r;
                float val = acc[i][j][r] + bs;
                if (RELU) val = fmaxf(val, 0.f);
                if constexpr (OUT_MODE == 0)
                    Cf[(size_t)row * N + col] = val;
                if constexpr (OUT_MODE == 2)
                    Cb[(size_t)row * N + col] = (bf16)(val * bscale);
                if constexpr (OUT_MODE == 3)
                    Cb[(size_t)col * SQ + row] = (bf16)val;
            }
        }
    }
}

// ---------------------------------------------------------------------------
// MFMA flash attention v7: v5 pipeline (swapped QK^T, no-max softmax, LDS P
// relayout, K=32 PV) + TWO Q-subtiles per wave (QBLK=128) sharing the K/V
// register fragments (halves per-CU cache-line traffic, doubles ILP) +
// XCD-aware block swizzle (blocks sharing (head,split) -> same XCD L2).
// kb pre-scaled by LOG2E/sqrt(32); p = exp2(s); merge = sum(o)/sum(l).
// ---------------------------------------------------------------------------
__global__ __launch_bounds__(256)
void flash_attn7(const bf16* __restrict__ qb, const bf16* __restrict__ kb,
                 const bf16* __restrict__ vT, bf16* __restrict__ Op,
                 float* __restrict__ Lp) {
    // grid (32, NH, NSPLIT) = 1024 blocks; remap so each XCD owns 4 (h,sp) pairs
    const int fid = blockIdx.x + 32 * (blockIdx.y + NH * blockIdx.z);
    const int nid = (fid & 7) * 128 + (fid >> 3);
    const int q0 = (nid & 31) * 128;
    const int h  = (nid >> 5) & 7;
    const int sp = nid >> 8;

    const int tid = threadIdx.x;
    const int w = tid >> 6, l = tid & 63;
    const int l15 = l & 15, lg = l >> 4;

    __shared__ unsigned int Sb[4][2][8][72];   // [wave][sub][slot][lane] 18KB

    bf16x8 aq0 = *reinterpret_cast<const bf16x8*>(
        &qb[(size_t)(q0 + w * 16 + l15) * CCH + h * HD + lg * 8]);
    bf16x8 aq1 = *reinterpret_cast<const bf16x8*>(
        &qb[(size_t)(q0 + 64 + w * 16 + l15) * CCH + h * HD + lg * 8]);

    float lac0 = 0.f, lac1 = 0.f;
    f32x4 o0[2] = {{0.f, 0.f, 0.f, 0.f}, {0.f, 0.f, 0.f, 0.f}};
    f32x4 o1[2] = {{0.f, 0.f, 0.f, 0.f}, {0.f, 0.f, 0.f, 0.f}};

    const bf16* kfrag = &kb[(size_t)l15 * CCH + h * HD + lg * 8];
    const bf16* vfrag = &vT[(size_t)(h * HD + l15) * SQ + lg * 8];

    const int kt0 = sp * (SQ / NSPLIT / 64);
    const int kt1 = kt0 + (SQ / NSPLIT / 64);

    for (int kt = kt0; kt < kt1; ++kt) {
        const int kb0 = kt * 64;

        // --- shared K/V fragments for this tile (reused by both subtiles) ---
        bf16x8 kf[4], vf[2][2];
        #pragma unroll
        for (int t = 0; t < 4; ++t)
            kf[t] = *reinterpret_cast<const bf16x8*>(kfrag + (size_t)(kb0 + t * 16) * CCH);
        #pragma unroll
        for (int dh = 0; dh < 2; ++dh)
            #pragma unroll
            for (int kh = 0; kh < 2; ++kh)
                vf[dh][kh] = *reinterpret_cast<const bf16x8*>(
                    vfrag + (size_t)dh * 16 * SQ + kb0 + kh * 32);

        // --- S^T = K·Q^T for both subtiles ---
        f32x4 s0[4], s1[4];
        #pragma unroll
        for (int t = 0; t < 4; ++t)
            s0[t] = __builtin_amdgcn_mfma_f32_16x16x32_bf16(kf[t], aq0, (f32x4){0.f, 0.f, 0.f, 0.f}, 0, 0, 0);
        #pragma unroll
        for (int t = 0; t < 4; ++t)
            s1[t] = __builtin_amdgcn_mfma_f32_16x16x32_bf16(kf[t], aq1, (f32x4){0.f, 0.f, 0.f, 0.f}, 0, 0, 0);

        // --- p = exp2(s); pack + lane-major LDS store (per-wave, no barrier) ---
        #pragma unroll
        for (int t = 0; t < 4; ++t) {
            float p0 = exp2f(s0[t][0]), p1 = exp2f(s0[t][1]);
            float p2 = exp2f(s0[t][2]), p3 = exp2f(s0[t][3]);
            lac0 += (p0 + p1) + (p2 + p3);
            unsigned int u0 = __builtin_bit_cast(unsigned int, p0) + 0x8000u;
            unsigned int u1 = __builtin_bit_cast(unsigned int, p1) + 0x8000u;
            unsigned int u2 = __builtin_bit_cast(unsigned int, p2) + 0x8000u;
            unsigned int u3 = __builtin_bit_cast(unsigned int, p3) + 0x8000u;
            Sb[w][0][t * 2 + 0][l] = __builtin_amdgcn_perm(u1, u0, 0x07060302u);
            Sb[w][0][t * 2 + 1][l] = __builtin_amdgcn_perm(u3, u2, 0x07060302u);
        }
        #pragma unroll
        for (int t = 0; t < 4; ++t) {
            float p0 = exp2f(s1[t][0]), p1 = exp2f(s1[t][1]);
            float p2 = exp2f(s1[t][2]), p3 = exp2f(s1[t][3]);
            lac1 += (p0 + p1) + (p2 + p3);
            unsigned int u0 = __builtin_bit_cast(unsigned int, p0) + 0x8000u;
            unsigned int u1 = __builtin_bit_cast(unsigned int, p1) + 0x8000u;
            unsigned int u2 = __builtin_bit_cast(unsigned int, p2) + 0x8000u;
            unsigned int u3 = __builtin_bit_cast(unsigned int, p3) + 0x8000u;
            Sb[w][1][t * 2 + 0][l] = __builtin_amdgcn_perm(u1, u0, 0x07060302u);
            Sb[w][1][t * 2 + 1][l] = __builtin_amdgcn_perm(u3, u2, 0x07060302u);
        }

        // --- PV: O^T += V^T · P^T over two 32-key halves, both subtiles ---
        #pragma unroll
        for (int kh = 0; kh < 2; ++kh) {
            const int sbase = kh * 4 + (lg >> 1) * 2;
            const int i0 = l15 + 16 * ((lg & 1) * 2);
            const int i1 = i0 + 16;
            union { unsigned int u[4]; bf16x8 v; } pb0, pb1;
            pb0.u[0] = Sb[w][0][sbase + 0][i0];
            pb0.u[1] = Sb[w][0][sbase + 1][i0];
            pb0.u[2] = Sb[w][0][sbase + 0][i1];
            pb0.u[3] = Sb[w][0][sbase + 1][i1];
            pb1.u[0] = Sb[w][1][sbase + 0][i0];
            pb1.u[1] = Sb[w][1][sbase + 1][i0];
            pb1.u[2] = Sb[w][1][sbase + 0][i1];
            pb1.u[3] = Sb[w][1][sbase + 1][i1];
            #pragma unroll
            for (int dh = 0; dh < 2; ++dh) {
                o0[dh] = __builtin_amdgcn_mfma_f32_16x16x32_bf16(vf[dh][kh], pb0.v, o0[dh], 0, 0, 0);
                o1[dh] = __builtin_amdgcn_mfma_f32_16x16x32_bf16(vf[dh][kh], pb1.v, o1[dh], 0, 0, 0);
            }
        }
    }

    // --- end-of-split: reduce l across the 4 lane-groups; write raw o,l ---
    lac0 += __shfl_xor(lac0, 16);
    lac0 += __shfl_xor(lac0, 32);
    lac1 += __shfl_xor(lac1, 16);
    lac1 += __shfl_xor(lac1, 32);

    const size_t obase = ((size_t)sp * NH + h) * HD;
    #pragma unroll
    for (int dh = 0; dh < 2; ++dh)
        #pragma unroll
        for (int r = 0; r < 4; ++r) {
            Op[(obase + dh * 16 + lg * 4 + r) * SQ + q0 + w * 16 + l15] = (bf16)o0[dh][r];
            Op[(obase + dh * 16 + lg * 4 + r) * SQ + q0 + 64 + w * 16 + l15] = (bf16)o1[dh][r];
        }
    if (lg == 0) {
        Lp[((size_t)sp * NH + h) * SQ + q0 + w * 16 + l15] = lac0;
        Lp[((size_t)sp * NH + h) * SQ + q0 + 64 + w * 16 + l15] = lac1;
    }
}

// ---------------------------------------------------------------------------
// Merge NSPLIT raw partial O^T [d][q] tiles -> atb [S][C] bf16.
// out = (sum_sp o_sp) / (sum_sp l_sp).  Block = (64 q, head).
// ---------------------------------------------------------------------------
__global__ __launch_bounds__(256)
void attn_merge3(const bf16* __restrict__ Op, const float* __restrict__ Lp,
                 bf16* __restrict__ atb) {
    const int h = blockIdx.y;
    const int q0 = blockIdx.x * 64;
    const int t = threadIdx.x;
    __shared__ float sInv[64];
    __shared__ float trans[32][65];

    if (t < 64) {
        float L = 0.f;
        #pragma unroll
        for (int sp = 0; sp < NSPLIT; ++sp)
            L += Lp[((size_t)sp * NH + h) * SQ + q0 + t];
        sInv[t] = 1.0f / L;
    }
    __syncthreads();

    const int q = t & 63, dg = t >> 6;
    float a[8] = {0.f, 0.f, 0.f, 0.f, 0.f, 0.f, 0.f, 0.f};
    for (int sp = 0; sp < NSPLIT; ++sp) {
        const size_t rb = ((size_t)sp * NH + h) * HD;
        #pragma unroll
        for (int i = 0; i < 8; ++i) {
            const int d = i * 4 + dg;
            a[i] += (float)Op[(rb + d) * SQ + q0 + q];
        }
    }
    const float invq = sInv[q];
    #pragma unroll
    for (int i = 0; i < 8; ++i)
        trans[i * 4 + dg][q] = a[i] * invq;
    __syncthreads();

    const int oq = t >> 2, od = (t & 3) * 8;
    bf16x8 o8;
    #pragma unroll
    for (int j = 0; j < 8; ++j) o8[j] = (bf16)trans[od + j][oq];
    *reinterpret_cast<bf16x8*>(&atb[(size_t)(q0 + oq) * CCH + h * HD + od]) = o8;
}

// ---------------------------------------------------------------------------
// Fused residual add + LayerNorm over C=256; optional bf16 secondary output.
// ---------------------------------------------------------------------------
template <typename TA, bool DUAL>
__global__ __launch_bounds__(256)
void add_ln(const TA* __restrict__ a, const float* __restrict__ b,
            const float* __restrict__ g, const float* __restrict__ beta,
            float* __restrict__ out, bf16* __restrict__ outb) {
    const int s = blockIdx.x;
    const int c = threadIdx.x;
    float val = (float)a[(size_t)s * CCH + c] + b[(size_t)s * CCH + c];
    float sum = val, sq = val * val;
    #pragma unroll
    for (int off = 1; off < 64; off <<= 1) {
        sum += __shfl_xor(sum, off);
        sq  += __shfl_xor(sq, off);
    }
    __shared__ float ssum[4], ssq[4];
    int w = c >> 6;
    if ((c & 63) == 0) { ssum[w] = sum; ssq[w] = sq; }
    __syncthreads();
    sum = ssum[0] + ssum[1] + ssum[2] + ssum[3];
    sq  = ssq[0] + ssq[1] + ssq[2] + ssq[3];
    float mu = sum * (1.0f / CCH);
    float var = sq * (1.0f / CCH) - mu * mu;
    float rs = rsqrtf(var + LN_EPS);
    float res = (val - mu) * rs * g[c] + beta[c];
    out[(size_t)s * CCH + c] = res;
    if constexpr (DUAL) outb[(size_t)s * CCH + c] = (bf16)res;
}

// ---------------------------------------------------------------------------
// Final transpose: in [S][C] f32 -> out [C][S] f32
// ---------------------------------------------------------------------------
__global__ __launch_bounds__(256)
void transpose_sc_cs(const float* __restrict__ in, float* __restrict__ out) {
    __shared__ float tile[32][33];
    const int s0 = blockIdx.x * 32;
    const int c0 = blockIdx.y * 32;
    const int tx = threadIdx.x & 31;
    const int ty = threadIdx.x >> 5;
    #pragma unroll
    for (int i = 0; i < 32; i += 8)
        tile[ty + i][tx] = in[(size_t)(s0 + ty + i) * CCH + c0 + tx];
    __syncthreads();
    #pragma unroll
    for (int i = 0; i < 32; i += 8)
        out[(size_t)(c0 + ty + i) * SQ + s0 + tx] = tile[tx][ty + i];
}

// ---------------------------------------------------------------------------
extern "C" void kernel_launch(void* const* d_in, const int* in_sizes, int n_in,
                              void* d_out, int out_size, void* d_ws, size_t ws_size,
                              hipStream_t stream) {
    const float* lidar = (const float*)d_in[0];
    const float* image = (const float*)d_in[1];
    const float* Wq  = (const float*)d_in[2];
    const float* bq  = (const float*)d_in[3];
    const float* Wk  = (const float*)d_in[4];
    const float* bk  = (const float*)d_in[5];
    const float* Wv  = (const float*)d_in[6];
    const float* bv  = (const float*)d_in[7];
    const float* Wo  = (const float*)d_in[8];
    const float* bo  = (const float*)d_in[9];
    const float* g1  = (const float*)d_in[10];
    const float* b1  = (const float*)d_in[11];
    const float* W1  = (const float*)d_in[12];
    const float* bf1 = (const float*)d_in[13];
    const float* W2  = (const float*)d_in[14];
    const float* bf2 = (const float*)d_in[15];
    const float* g2  = (const float*)d_in[16];
    const float* b2  = (const float*)d_in[17];
    float* out = (float*)d_out;

    // workspace layout (aliased; peak 23.5 MB)
    char* ws = (char*)d_ws;
    const size_t KB = 1024, MBy = 1024 * 1024;
    bf16* xT   = (bf16*)(ws + 0);                    // [0,2M)    dead after q-gemm
    bf16* yT   = (bf16*)(ws + 2 * MBy);              // [2,4M)    dead after v-gemm
    bf16* WqT  = (bf16*)(ws + 4 * MBy);              // weights [4,5.5M)
    bf16* WkT  = (bf16*)(ws + 4 * MBy + 128 * KB);
    bf16* WvT  = (bf16*)(ws + 4 * MBy + 256 * KB);
    bf16* WoT  = (bf16*)(ws + 4 * MBy + 384 * KB);
    bf16* W1T  = (bf16*)(ws + 4 * MBy + 512 * KB);
    bf16* W2T  = (bf16*)(ws + 5 * MBy);
    bf16* qb   = (bf16*)(ws + 5 * MBy + 512 * KB);   // [5.5,7.5M)  live -> ln1 (residual)
    bf16* kbb  = (bf16*)(ws + 7 * MBy + 512 * KB);   // [7.5,9.5M)  live -> flash
    bf16* vTb  = (bf16*)(ws + 9 * MBy + 512 * KB);   // [9.5,11.5M) live -> flash
    bf16* Op   = (bf16*)(ws + 11 * MBy + 512 * KB);  // [11.5,19.5M) partials, dead after merge
    float* Lp  = (float*)(ws + 20 * MBy);            // [20,20.5M)
    bf16* atb  = (bf16*)(ws + 0);                    // [0,2M)    reuses xT; dead after Wo
    float* o   = (float*)(ws + 7 * MBy + 512 * KB);  // [7.5,11.5M) reuses kbb/vTb; dead after ln1
    float* ln1 = (float*)(ws + 11 * MBy + 512 * KB); // [11.5,15.5M) reuses Op; live -> ln2
    bf16* ln1b = (bf16*)(ws + 0);                    // [0,2M)    reuses atb; dead after ffn1
    bf16* h1   = (bf16*)(ws + 15 * MBy + 512 * KB);  // [15.5,23.5M) dead after ffn2
    float* h2  = (float*)(ws + 5 * MBy + 512 * KB);  // [5.5,9.5M)  reuses qb/o; dead after ln2
    float* ln2 = (float*)(ws + 0);                   // [0,4M)    reuses ln1b/yT

    // 1/sqrt(32) * log2(e) folded into K -> scores already in log2 domain
    const float qscale = 0.17677669529663687f * 1.4426950408889634f;
    dim3 blk(256);

    cvt_inputs<<<dim3(SQ / 32, CCH / 32, 2), blk, 0, stream>>>(lidar, image, xT, yT);
    cvt_weights<<<dim3(768), blk, 0, stream>>>(Wq, Wk, Wv, Wo, W1, W2,
                                               WqT, WkT, WvT, WoT, W1T, W2T);
    // projections: q bf16 (unscaled, also residual), k bf16 (pre-scaled), v bf16 transposed
    gemm_mfma<256, 2, false><<<dim3(64, 4), blk, 0, stream>>>(xT, WqT, bq, nullptr, qb, 256, 1.f);
    gemm_mfma<256, 2, false><<<dim3(64, 4), blk, 0, stream>>>(yT, WkT, bk, nullptr, kbb, 256, qscale);
    gemm_mfma<256, 3, false><<<dim3(64, 4), blk, 0, stream>>>(yT, WvT, bv, nullptr, vTb, 256, 1.f);
    // attention (split-KV, swapped-operand, no-max softmax, dual-Q waves) + merge
    flash_attn7<<<dim3(SQ / 128, NH, NSPLIT), blk, 0, stream>>>(qb, kbb, vTb, Op, Lp);
    attn_merge3<<<dim3(SQ / 64, NH), blk, 0, stream>>>(Op, Lp, atb);
    // output projection
    gemm_mfma<256, 0, false><<<dim3(64, 4), blk, 0, stream>>>(atb, WoT, bo, o, nullptr, 256, 1.f);
    // LN1(q + o) -> f32 + bf16
    add_ln<bf16, true><<<SQ, blk, 0, stream>>>(qb, o, g1, b1, ln1, ln1b);
    // FFN
    gemm_mfma<256, 2, true ><<<dim3(64, 16), blk, 0, stream>>>(ln1b, W1T, bf1, nullptr, h1, 1024, 1.f);
    gemm_mfma<1024, 0, false><<<dim3(64, 4), blk, 0, stream>>>(h1, W2T, bf2, h2, nullptr, 256, 1.f);
    // LN2(ln1 + h2)
    add_ln<float, false><<<SQ, blk, 0, stream>>>(ln1, h2, g2, b2, ln2, nullptr);
    // final [S][C] -> [C][S]
    transpose_sc_cs<<<dim3(SQ / 32, CCH / 32), blk, 0, stream>>>(ln2, out);
}